// Round 4
// baseline (308.600 us; speedup 1.0000x reference)
//
#include <hip/hip_runtime.h>

typedef unsigned short u16;
typedef __attribute__((ext_vector_type(8))) short short8;
typedef __attribute__((ext_vector_type(4))) unsigned short u16x4;
typedef __attribute__((ext_vector_type(4))) float f32x4;

#define N_TOKENS 32768
#define EMBED 512
#define NCLS 16
#define NBATCH 8
#define NHEAD 8
#define DHEAD 64

__device__ __forceinline__ u16 f2bf(float f) {
  unsigned u = __float_as_uint(f);
  u += 0x7fffu + ((u >> 16) & 1u);   // RNE
  return (u16)(u >> 16);
}

__device__ __forceinline__ void async16(const u16* g, u16* l) {
  __builtin_amdgcn_global_load_lds(
      (__attribute__((address_space(1))) const unsigned int*)(const void*)g,
      (__attribute__((address_space(3))) unsigned int*)(void*)l,
      16, 0, 0);
}

// ---------------- K/V projection, split-K x2 ----------------
// Two consecutive threads share one output; each does half the E-dot (64 float4),
// combined with one shfl_xor. Halves the serial FMA chain, doubles resident waves.
__global__ __launch_bounds__(256) void kvproj_kernel(
    const float* __restrict__ key, const float* __restrict__ val,
    const float* __restrict__ Wk, const float* __restrict__ bk,
    const float* __restrict__ Wv, const float* __restrict__ bv,
    float* __restrict__ kproj, float* __restrict__ vproj) {
  int t = blockIdx.x * blockDim.x + threadIdx.x;   // [0, 2*131072)
  int o = t >> 1;                                   // output id [0, 131072)
  int half = t & 1;
  const bool isV = o >= 65536;                      // wave-uniform
  int idx = o & 65535;
  int f = idx & 511;
  int bl = idx >> 9;
  int l = bl & 15;
  int b = bl >> 4;
  const float* src = isV ? val : key;
  const float* W = isV ? Wv : Wk;
  const float* bias = isV ? bv : bk;
  const float4* s4 = (const float4*)(src + (size_t)l * (NBATCH * EMBED) + (size_t)b * EMBED) + half * 64;
  const float4* w4 = (const float4*)(W + (size_t)f * EMBED) + half * 64;
  float acc = 0.f;
#pragma unroll 8
  for (int e = 0; e < 64; e++) {
    float4 a = s4[e], w = w4[e];
    acc += a.x * w.x + a.y * w.y + a.z * w.z + a.w * w.w;
  }
  acc += __shfl_xor(acc, 1);
  if (half == 0) {
    acc += bias[f];
    if (!isV) {
      kproj[((size_t)(b * EMBED + f)) * NCLS + l] = acc;           // [b][h][d][l]
    } else {
      int h = f >> 6, d = f & 63;
      vproj[(size_t)b * 8192 + (size_t)h * 1024 + l * 64 + d] = acc;  // [b][h][l][d]
    }
  }
}

// ---------------- merged build: Kq / WoV / sb in one launch ----------------
// blocks [0,2048): Kq[b][hl][e] = sum_d Wq[h*64+d][e] * kproj[b,h,d,l]  (bf16)
// blocks [2048,4096): WoV[b][f][hl] = sum_d vproj[b,h,l,d] * Wo[f][h*64+d] (bf16)
// blocks [4096,4100): sb[b][hl] = sum_d bq[h*64+d] * kproj[b,h,d,l]
__global__ __launch_bounds__(256) void build_all(
    const float* __restrict__ kproj, const float* __restrict__ vproj,
    const float* __restrict__ Wq, const float* __restrict__ bq,
    const float* __restrict__ Wo,
    u16* __restrict__ Kqb, u16* __restrict__ WoVb, float* __restrict__ sb) {
  const int blk = blockIdx.x;
  if (blk < 2048) {
    int t = blk * 256 + threadIdx.x;   // 8*128*512
    int e = t & 511;
    int hl = (t >> 9) & 127;
    int b = t >> 16;
    int h = hl >> 4, l = hl & 15;
    const float* kp = kproj + (size_t)b * 8192 + h * 1024 + l;
    const float* wq = Wq + (size_t)(h * 64) * 512 + e;
    float acc = 0.f;
#pragma unroll 16
    for (int d = 0; d < 64; d++) acc += kp[d * 16] * wq[d * 512];
    Kqb[t] = f2bf(acc);
  } else if (blk < 4096) {
    int t = (blk - 2048) * 256 + threadIdx.x;   // 8*512*128
    int hl = t & 127;
    int f = (t >> 7) & 511;
    int b = t >> 16;
    int h = hl >> 4, l = hl & 15;
    const float* vp = vproj + (size_t)b * 8192 + h * 1024 + l * 64;
    const float* wo = Wo + (size_t)f * 512 + h * 64;
    float acc = 0.f;
#pragma unroll 16
    for (int d = 0; d < 64; d++) acc += vp[d] * wo[d];
    WoVb[t] = f2bf(acc);
  } else {
    int t = (blk - 4096) * 256 + threadIdx.x;   // 1024
    int hl = t & 127, b = t >> 7;
    int h = hl >> 4, l = hl & 15;
    const float* kp = kproj + (size_t)b * 8192 + h * 1024 + l;
    const float* q = bq + h * 64;
    float acc = 0.f;
#pragma unroll
    for (int d = 0; d < 64; d++) acc += q[d] * kp[d * 16];
    sb[t] = acc;
  }
}

// ---------------- fused: scores GEMM + softmax + out GEMM ----------------
// v4: 64-token tiles, grid 512, 4 waves, LDS 32 KB, launch_bounds(256,3)
// -> all blocks resident (>=2 blocks/CU). Phase 1 (m97 structure): Kq panel
// k-slices staged via global_load_lds double-buffer (one __syncthreads per
// K-step, stage-next after barrier overlaps compute); wave owns 16 EXCLUSIVE
// rows x all 128 cols (query read once, fp32->bf16 fused, prefetched one step
// ahead); 8 ds_read_b128 + 8 MFMA per step. Softmax per head via 16-lane shfl;
// P -> swizzled LDS. Phase 2: wave owns 128 f-cols; WoV fragments direct from
// L2; NORMAL stores (back-to-back 64B chunks -> L2 line combine; v3's
// nontemporal caused ~1.8x write amplification).
__global__ __launch_bounds__(256, 3) void fused_attn(
    const float* __restrict__ query, const u16* __restrict__ Kqb,
    const u16* __restrict__ WoVb, const float* __restrict__ sb,
    const float* __restrict__ bo, const int* __restrict__ bidx,
    float* __restrict__ out) {
  __shared__ __align__(16) u16 Bs[2][128 * 32];   // 16 KB: Kq k-slice, dbuf
  __shared__ __align__(16) u16 Ps[64 * 128];      // 16 KB: P, XOR-swizzled
  const int tid = threadIdx.x;
  const int lane = tid & 63;
  const int wave = tid >> 6;
  const int quad = lane >> 4;
  const int l16 = lane & 15;
  const int m0 = blockIdx.x * 64;
  const int bFirst = bidx[m0];
  const int bLast = bidx[m0 + 63];

  // staging coords: 512 chunks of 16B per 8KB k-slice; thread owns chunks
  // tid and tid+256. chunk c -> row=c>>2, kpart=c&3; source pre-swizzled.
  const int r0 = tid >> 2, r1 = r0 + 64;
  const int lg0 = (tid & 3) ^ ((r0 >> 1) & 3);
  const int lg1 = (tid & 3) ^ ((r1 >> 1) & 3);
  const size_t boff0 = (size_t)r0 * 512 + lg0 * 8;
  const size_t boff1 = (size_t)r1 * 512 + lg1 * 8;

  // per-row batch for predicated stores (phase 2: wave covers all 64 rows)
  int rowb[4][4];
#pragma unroll
  for (int mi = 0; mi < 4; mi++)
#pragma unroll
    for (int r = 0; r < 4; r++) rowb[mi][r] = bidx[m0 + mi * 16 + quad * 4 + r];

  // phase-1 A pointer: wave-exclusive row, quad picks 8-elem k-slice
  const float* pA = query + (size_t)(m0 + wave * 16 + l16) * 512 + quad * 8;

  for (int bb = bFirst; bb <= bLast; bb++) {
    const u16* Bq = Kqb + (size_t)bb * 65536;

    // prologue: stage k-slice 0 into buf 0; prefetch A slice 0
    async16(Bq + boff0, &Bs[0][tid * 8]);
    async16(Bq + boff1, &Bs[0][tid * 8 + 2048]);
    float4 na0 = *(const float4*)(pA);
    float4 na1 = *(const float4*)(pA + 4);

    f32x4 acc1[8];
#pragma unroll
    for (int j = 0; j < 8; j++) acc1[j] = (f32x4){0.f, 0.f, 0.f, 0.f};

    for (int t = 0; t < 16; t++) {
      __syncthreads();                     // drains vmcnt -> buf[t&1] + A(t) ready
      const int cur = t & 1;
      if (t < 15) {                        // stage next k-slice; overlaps MFMA below
        const int ko = (t + 1) * 32;
        async16(Bq + boff0 + ko, &Bs[cur ^ 1][tid * 8]);
        async16(Bq + boff1 + ko, &Bs[cur ^ 1][tid * 8 + 2048]);
      }
      float4 a0 = na0, a1 = na1;
      if (t < 15) {                        // prefetch A(t+1), one step of latency hiding
        na0 = *(const float4*)(pA + (t + 1) * 32);
        na1 = *(const float4*)(pA + (t + 1) * 32 + 4);
      }
      short8 af;
      af[0] = (short)f2bf(a0.x); af[1] = (short)f2bf(a0.y);
      af[2] = (short)f2bf(a0.z); af[3] = (short)f2bf(a0.w);
      af[4] = (short)f2bf(a1.x); af[5] = (short)f2bf(a1.y);
      af[6] = (short)f2bf(a1.z); af[7] = (short)f2bf(a1.w);
#pragma unroll
      for (int ni = 0; ni < 8; ni++) {
        const int rw = ni * 16 + l16;
        short8 bfr = *(const short8*)&Bs[cur][rw * 32 + ((quad ^ ((rw >> 1) & 3)) << 3)];
        acc1[ni] = __builtin_amdgcn_mfma_f32_16x16x32_bf16(af, bfr, acc1[ni], 0, 0, 0);
      }
    }

    // ---- softmax over each head's 16 l-cols (16-lane shfl), P -> LDS ----
    float sbv[8];
#pragma unroll
    for (int ni = 0; ni < 8; ni++) sbv[ni] = sb[bb * 128 + ni * 16 + l16];
#pragma unroll
    for (int r = 0; r < 4; r++) {
      const int row = wave * 16 + quad * 4 + r;   // wave-exclusive rows
#pragma unroll
      for (int ni = 0; ni < 8; ni++) {
        float v = acc1[ni][r] + sbv[ni];
        float mx = v;
        mx = fmaxf(mx, __shfl_xor(mx, 1));
        mx = fmaxf(mx, __shfl_xor(mx, 2));
        mx = fmaxf(mx, __shfl_xor(mx, 4));
        mx = fmaxf(mx, __shfl_xor(mx, 8));
        float ev = __expf((v - mx) * 0.125f);   // scale = D^-0.5
        float s = ev;
        s += __shfl_xor(s, 1);
        s += __shfl_xor(s, 2);
        s += __shfl_xor(s, 4);
        s += __shfl_xor(s, 8);
        const int col = ni * 16 + l16;
        Ps[row * 128 + (((col >> 3) ^ (row & 7)) << 3) + (col & 7)] = f2bf(ev / s);
      }
    }
    __syncthreads();   // all P stripes visible

    // ---- phase 2: out[64,512] = P x WoV[bb]^T; wave owns 128 f-cols ----
    const u16* Wv = WoVb + (size_t)bb * 65536;
#pragma unroll
    for (int h2 = 0; h2 < 2; h2++) {
      const int f0 = wave * 128 + h2 * 64;
      f32x4 acc2[4][4];
#pragma unroll
      for (int i = 0; i < 4; i++)
#pragma unroll
        for (int j = 0; j < 4; j++) acc2[i][j] = (f32x4){0.f, 0.f, 0.f, 0.f};
#pragma unroll
      for (int kk = 0; kk < 4; kk++) {
        short8 paf[4], bf2[4];
#pragma unroll
        for (int mi = 0; mi < 4; mi++) {
          const int row = mi * 16 + l16;
          paf[mi] = *(const short8*)&Ps[row * 128 + (((kk * 4 + quad) ^ (row & 7)) << 3)];
        }
#pragma unroll
        for (int ni = 0; ni < 4; ni++) {
          const int fr = f0 + ni * 16 + l16;
          bf2[ni] = *(const short8*)(Wv + (size_t)fr * 128 + kk * 32 + quad * 8);
        }
#pragma unroll
        for (int mi = 0; mi < 4; mi++)
#pragma unroll
          for (int ni = 0; ni < 4; ni++)
            acc2[mi][ni] = __builtin_amdgcn_mfma_f32_16x16x32_bf16(paf[mi], bf2[ni], acc2[mi][ni], 0, 0, 0);
      }
      float bov[4];
#pragma unroll
      for (int ni = 0; ni < 4; ni++) bov[ni] = bo[f0 + ni * 16 + l16];
#pragma unroll
      for (int mi = 0; mi < 4; mi++)
#pragma unroll
        for (int r = 0; r < 4; r++) {
          if (rowb[mi][r] == bb) {
            const size_t row = m0 + mi * 16 + quad * 4 + r;
#pragma unroll
            for (int ni = 0; ni < 4; ni++)
              out[row * 512 + f0 + ni * 16 + l16] = acc2[mi][ni][r] + bov[ni];
          }
        }
    }
    __syncthreads();   // Ps/Bs safe to overwrite next bb
  }
}

extern "C" void kernel_launch(void* const* d_in, const int* in_sizes, int n_in,
                              void* d_out, int out_size, void* d_ws, size_t ws_size,
                              hipStream_t stream) {
  const float* query = (const float*)d_in[0];
  const float* keyt = (const float*)d_in[1];
  const float* valt = (const float*)d_in[2];
  const int* bidx = (const int*)d_in[3];
  // d_in[4] = batch_size (scalar, fixed = 8)
  const float* Wq = (const float*)d_in[5];
  const float* bq = (const float*)d_in[6];
  const float* Wk = (const float*)d_in[7];
  const float* bk = (const float*)d_in[8];
  const float* Wv = (const float*)d_in[9];
  const float* bv = (const float*)d_in[10];
  const float* Wo = (const float*)d_in[11];
  const float* bo = (const float*)d_in[12];
  float* out = (float*)d_out;

  // workspace layout (bytes)
  unsigned char* w = (unsigned char*)d_ws;
  float* kproj = (float*)(w + 41943040ull);   //    262,144: [B,H,D,L]
  float* vproj = (float*)(w + 42205184ull);   //    262,144: [B,H,L,D]
  u16* Kqb = (u16*)(w + 42467328ull);         //  1,048,576: [B,128,512] bf16
  u16* WoVb = (u16*)(w + 43515904ull);        //  1,048,576: [B,512,128] bf16
  float* sb = (float*)(w + 44564480ull);      //      4,096: [B,128]

  // 1) K/V projections (fp32, split-K x2)
  kvproj_kernel<<<1024, 256, 0, stream>>>(keyt, valt, Wk, bk, Wv, bv, kproj, vproj);

  // 2) fold Wq through k, Wo through v, and sb — one launch
  build_all<<<4100, 256, 0, stream>>>(kproj, vproj, Wq, bq, Wo, Kqb, WoVb, sb);

  // 3) fused: fp32 query -> scores -> softmax -> out
  fused_attn<<<N_TOKENS / 64, 256, 0, stream>>>(query, Kqb, WoVb, sb, bo, bidx, out);
}

// Round 5
// 277.260 us; speedup vs baseline: 1.1130x; 1.1130x over previous
//
#include <hip/hip_runtime.h>

typedef unsigned short u16;
typedef __attribute__((ext_vector_type(8))) short short8;
typedef __attribute__((ext_vector_type(4))) unsigned short u16x4;
typedef __attribute__((ext_vector_type(4))) float f32x4;

#define N_TOKENS 32768
#define EMBED 512
#define NCLS 16
#define NBATCH 8
#define NHEAD 8
#define DHEAD 64

__device__ __forceinline__ u16 f2bf(float f) {
  unsigned u = __float_as_uint(f);
  u += 0x7fffu + ((u >> 16) & 1u);   // RNE
  return (u16)(u >> 16);
}

__device__ __forceinline__ void async16(const u16* g, u16* l) {
  __builtin_amdgcn_global_load_lds(
      (__attribute__((address_space(1))) const unsigned int*)(const void*)g,
      (__attribute__((address_space(3))) unsigned int*)(void*)l,
      16, 0, 0);
}

// ---------------- K/V projection, split-K x2 ----------------
__global__ __launch_bounds__(256) void kvproj_kernel(
    const float* __restrict__ key, const float* __restrict__ val,
    const float* __restrict__ Wk, const float* __restrict__ bk,
    const float* __restrict__ Wv, const float* __restrict__ bv,
    float* __restrict__ kproj, float* __restrict__ vproj) {
  int t = blockIdx.x * blockDim.x + threadIdx.x;   // [0, 2*131072)
  int o = t >> 1;                                   // output id [0, 131072)
  int half = t & 1;
  const bool isV = o >= 65536;                      // wave-uniform
  int idx = o & 65535;
  int f = idx & 511;
  int bl = idx >> 9;
  int l = bl & 15;
  int b = bl >> 4;
  const float* src = isV ? val : key;
  const float* W = isV ? Wv : Wk;
  const float* bias = isV ? bv : bk;
  const float4* s4 = (const float4*)(src + (size_t)l * (NBATCH * EMBED) + (size_t)b * EMBED) + half * 64;
  const float4* w4 = (const float4*)(W + (size_t)f * EMBED) + half * 64;
  float acc = 0.f;
#pragma unroll 8
  for (int e = 0; e < 64; e++) {
    float4 a = s4[e], w = w4[e];
    acc += a.x * w.x + a.y * w.y + a.z * w.z + a.w * w.w;
  }
  acc += __shfl_xor(acc, 1);
  if (half == 0) {
    acc += bias[f];
    if (!isV) {
      kproj[((size_t)(b * EMBED + f)) * NCLS + l] = acc;           // [b][h][d][l]
    } else {
      int h = f >> 6, d = f & 63;
      vproj[(size_t)b * 8192 + (size_t)h * 1024 + l * 64 + d] = acc;  // [b][h][l][d]
    }
  }
}

// ---------------- merged build: Kq / WoV / sb in one launch ----------------
__global__ __launch_bounds__(256) void build_all(
    const float* __restrict__ kproj, const float* __restrict__ vproj,
    const float* __restrict__ Wq, const float* __restrict__ bq,
    const float* __restrict__ Wo,
    u16* __restrict__ Kqb, u16* __restrict__ WoVb, float* __restrict__ sb) {
  const int blk = blockIdx.x;
  if (blk < 2048) {
    int t = blk * 256 + threadIdx.x;   // 8*128*512
    int e = t & 511;
    int hl = (t >> 9) & 127;
    int b = t >> 16;
    int h = hl >> 4, l = hl & 15;
    const float* kp = kproj + (size_t)b * 8192 + h * 1024 + l;
    const float* wq = Wq + (size_t)(h * 64) * 512 + e;
    float acc = 0.f;
#pragma unroll 16
    for (int d = 0; d < 64; d++) acc += kp[d * 16] * wq[d * 512];
    Kqb[t] = f2bf(acc);
  } else if (blk < 4096) {
    int t = (blk - 2048) * 256 + threadIdx.x;   // 8*512*128
    int hl = t & 127;
    int f = (t >> 7) & 511;
    int b = t >> 16;
    int h = hl >> 4, l = hl & 15;
    const float* vp = vproj + (size_t)b * 8192 + h * 1024 + l * 64;
    const float* wo = Wo + (size_t)f * 512 + h * 64;
    float acc = 0.f;
#pragma unroll 16
    for (int d = 0; d < 64; d++) acc += vp[d] * wo[d];
    WoVb[t] = f2bf(acc);
  } else {
    int t = (blk - 4096) * 256 + threadIdx.x;   // 1024
    int hl = t & 127, b = t >> 7;
    int h = hl >> 4, l = hl & 15;
    const float* kp = kproj + (size_t)b * 8192 + h * 1024 + l;
    const float* q = bq + h * 64;
    float acc = 0.f;
#pragma unroll
    for (int d = 0; d < 64; d++) acc += q[d] * kp[d * 16];
    sb[t] = acc;
  }
}

// ---------------- fused: scores GEMM + softmax + out GEMM ----------------
// v5 changes vs v4 (same inner structure):
//  * TAIL FIX: grid = 2x tiles. slot0 handles bFirst; slot1 handles the
//    remaining batches of a boundary tile (usually one) and exits immediately
//    for the ~505 single-batch tiles. Work per block is uniform -> no 2x tail.
//  * NO occupancy cap: __launch_bounds__(256) only. v2-v4's (256,3/4) caps
//    forced VGPR spills (phase 2 needs ~116 live regs) -> scratch traffic =
//    the 1.85x WRITE amplification + latency poison. r1 (uncapped, 212 VGPR)
//    wrote exactly out-size. Let the allocator have what it needs.
__global__ __launch_bounds__(256) void fused_attn(
    const float* __restrict__ query, const u16* __restrict__ Kqb,
    const u16* __restrict__ WoVb, const float* __restrict__ sb,
    const float* __restrict__ bo, const int* __restrict__ bidx,
    float* __restrict__ out) {
  __shared__ __align__(16) u16 Bs[2][128 * 32];   // 16 KB: Kq k-slice, dbuf
  __shared__ __align__(16) u16 Ps[64 * 128];      // 16 KB: P, XOR-swizzled
  const int tid = threadIdx.x;
  const int lane = tid & 63;
  const int wave = tid >> 6;
  const int quad = lane >> 4;
  const int l16 = lane & 15;
  const int tileId = blockIdx.x >> 1;
  const int slot = blockIdx.x & 1;
  const int m0 = tileId * 64;
  const int bFirst = bidx[m0];
  const int bLast = bidx[m0 + 63];
  if (slot == 1 && bFirst == bLast) return;   // uniform exit, before any barrier
  const int b0 = (slot == 0) ? bFirst : bFirst + 1;
  const int b1 = (slot == 0) ? bFirst : bLast;

  // staging coords: 512 chunks of 16B per 8KB k-slice; thread owns chunks
  // tid and tid+256. chunk c -> row=c>>2, kpart=c&3; source pre-swizzled.
  const int r0 = tid >> 2, r1 = r0 + 64;
  const int lg0 = (tid & 3) ^ ((r0 >> 1) & 3);
  const int lg1 = (tid & 3) ^ ((r1 >> 1) & 3);
  const size_t boff0 = (size_t)r0 * 512 + lg0 * 8;
  const size_t boff1 = (size_t)r1 * 512 + lg1 * 8;

  // per-row batch for predicated stores (phase 2: wave covers all 64 rows)
  int rowb[4][4];
#pragma unroll
  for (int mi = 0; mi < 4; mi++)
#pragma unroll
    for (int r = 0; r < 4; r++) rowb[mi][r] = bidx[m0 + mi * 16 + quad * 4 + r];

  // phase-1 A pointer: wave-exclusive row, quad picks 8-elem k-slice
  const float* pA = query + (size_t)(m0 + wave * 16 + l16) * 512 + quad * 8;

  for (int bb = b0; bb <= b1; bb++) {
    const u16* Bq = Kqb + (size_t)bb * 65536;

    // prologue: stage k-slice 0 into buf 0; prefetch A slice 0
    async16(Bq + boff0, &Bs[0][tid * 8]);
    async16(Bq + boff1, &Bs[0][tid * 8 + 2048]);
    float4 na0 = *(const float4*)(pA);
    float4 na1 = *(const float4*)(pA + 4);

    f32x4 acc1[8];
#pragma unroll
    for (int j = 0; j < 8; j++) acc1[j] = (f32x4){0.f, 0.f, 0.f, 0.f};

    for (int t = 0; t < 16; t++) {
      __syncthreads();                     // drains vmcnt -> buf[t&1] + A(t) ready
      const int cur = t & 1;
      if (t < 15) {                        // stage next k-slice; overlaps MFMA below
        const int ko = (t + 1) * 32;
        async16(Bq + boff0 + ko, &Bs[cur ^ 1][tid * 8]);
        async16(Bq + boff1 + ko, &Bs[cur ^ 1][tid * 8 + 2048]);
      }
      float4 a0 = na0, a1 = na1;
      if (t < 15) {                        // prefetch A(t+1)
        na0 = *(const float4*)(pA + (t + 1) * 32);
        na1 = *(const float4*)(pA + (t + 1) * 32 + 4);
      }
      short8 af;
      af[0] = (short)f2bf(a0.x); af[1] = (short)f2bf(a0.y);
      af[2] = (short)f2bf(a0.z); af[3] = (short)f2bf(a0.w);
      af[4] = (short)f2bf(a1.x); af[5] = (short)f2bf(a1.y);
      af[6] = (short)f2bf(a1.z); af[7] = (short)f2bf(a1.w);
#pragma unroll
      for (int ni = 0; ni < 8; ni++) {
        const int rw = ni * 16 + l16;
        short8 bfr = *(const short8*)&Bs[cur][rw * 32 + ((quad ^ ((rw >> 1) & 3)) << 3)];
        acc1[ni] = __builtin_amdgcn_mfma_f32_16x16x32_bf16(af, bfr, acc1[ni], 0, 0, 0);
      }
    }

    // ---- softmax over each head's 16 l-cols (16-lane shfl), P -> LDS ----
    float sbv[8];
#pragma unroll
    for (int ni = 0; ni < 8; ni++) sbv[ni] = sb[bb * 128 + ni * 16 + l16];
#pragma unroll
    for (int r = 0; r < 4; r++) {
      const int row = wave * 16 + quad * 4 + r;   // wave-exclusive rows
#pragma unroll
      for (int ni = 0; ni < 8; ni++) {
        float v = acc1[ni][r] + sbv[ni];
        float mx = v;
        mx = fmaxf(mx, __shfl_xor(mx, 1));
        mx = fmaxf(mx, __shfl_xor(mx, 2));
        mx = fmaxf(mx, __shfl_xor(mx, 4));
        mx = fmaxf(mx, __shfl_xor(mx, 8));
        float ev = __expf((v - mx) * 0.125f);   // scale = D^-0.5
        float s = ev;
        s += __shfl_xor(s, 1);
        s += __shfl_xor(s, 2);
        s += __shfl_xor(s, 4);
        s += __shfl_xor(s, 8);
        const int col = ni * 16 + l16;
        Ps[row * 128 + (((col >> 3) ^ (row & 7)) << 3) + (col & 7)] = f2bf(ev / s);
      }
    }
    __syncthreads();   // all P stripes visible

    // ---- phase 2: out[64,512] = P x WoV[bb]^T; wave owns 128 f-cols ----
    const u16* Wv = WoVb + (size_t)bb * 65536;
#pragma unroll
    for (int h2 = 0; h2 < 2; h2++) {
      const int f0 = wave * 128 + h2 * 64;
      f32x4 acc2[4][4];
#pragma unroll
      for (int i = 0; i < 4; i++)
#pragma unroll
        for (int j = 0; j < 4; j++) acc2[i][j] = (f32x4){0.f, 0.f, 0.f, 0.f};
#pragma unroll
      for (int kk = 0; kk < 4; kk++) {
        short8 paf[4], bf2[4];
#pragma unroll
        for (int mi = 0; mi < 4; mi++) {
          const int row = mi * 16 + l16;
          paf[mi] = *(const short8*)&Ps[row * 128 + (((kk * 4 + quad) ^ (row & 7)) << 3)];
        }
#pragma unroll
        for (int ni = 0; ni < 4; ni++) {
          const int fr = f0 + ni * 16 + l16;
          bf2[ni] = *(const short8*)(Wv + (size_t)fr * 128 + kk * 32 + quad * 8);
        }
#pragma unroll
        for (int mi = 0; mi < 4; mi++)
#pragma unroll
          for (int ni = 0; ni < 4; ni++)
            acc2[mi][ni] = __builtin_amdgcn_mfma_f32_16x16x32_bf16(paf[mi], bf2[ni], acc2[mi][ni], 0, 0, 0);
      }
      float bov[4];
#pragma unroll
      for (int ni = 0; ni < 4; ni++) bov[ni] = bo[f0 + ni * 16 + l16];
#pragma unroll
      for (int mi = 0; mi < 4; mi++)
#pragma unroll
        for (int r = 0; r < 4; r++) {
          if (rowb[mi][r] == bb) {
            const size_t row = m0 + mi * 16 + quad * 4 + r;
#pragma unroll
            for (int ni = 0; ni < 4; ni++)
              out[row * 512 + f0 + ni * 16 + l16] = acc2[mi][ni][r] + bov[ni];
          }
        }
    }
    __syncthreads();   // Ps/Bs safe to overwrite next bb
  }
}

extern "C" void kernel_launch(void* const* d_in, const int* in_sizes, int n_in,
                              void* d_out, int out_size, void* d_ws, size_t ws_size,
                              hipStream_t stream) {
  const float* query = (const float*)d_in[0];
  const float* keyt = (const float*)d_in[1];
  const float* valt = (const float*)d_in[2];
  const int* bidx = (const int*)d_in[3];
  // d_in[4] = batch_size (scalar, fixed = 8)
  const float* Wq = (const float*)d_in[5];
  const float* bq = (const float*)d_in[6];
  const float* Wk = (const float*)d_in[7];
  const float* bk = (const float*)d_in[8];
  const float* Wv = (const float*)d_in[9];
  const float* bv = (const float*)d_in[10];
  const float* Wo = (const float*)d_in[11];
  const float* bo = (const float*)d_in[12];
  float* out = (float*)d_out;

  // workspace layout (bytes)
  unsigned char* w = (unsigned char*)d_ws;
  float* kproj = (float*)(w + 41943040ull);   //    262,144: [B,H,D,L]
  float* vproj = (float*)(w + 42205184ull);   //    262,144: [B,H,L,D]
  u16* Kqb = (u16*)(w + 42467328ull);         //  1,048,576: [B,128,512] bf16
  u16* WoVb = (u16*)(w + 43515904ull);        //  1,048,576: [B,512,128] bf16
  float* sb = (float*)(w + 44564480ull);      //      4,096: [B,128]

  // 1) K/V projections (fp32, split-K x2)
  kvproj_kernel<<<1024, 256, 0, stream>>>(keyt, valt, Wk, bk, Wv, bv, kproj, vproj);

  // 2) fold Wq through k, Wo through v, and sb — one launch
  build_all<<<4100, 256, 0, stream>>>(kproj, vproj, Wq, bq, Wo, Kqb, WoVb, sb);

  // 3) fused: fp32 query -> scores -> softmax -> out (tail-split grid)
  fused_attn<<<N_TOKENS / 64 * 2, 256, 0, stream>>>(query, Kqb, WoVb, sb, bo, bidx, out);
}